// Round 9
// baseline (322.774 us; speedup 1.0000x reference)
//
#include <hip/hip_runtime.h>

// GraphAttention on MI355X (gfx950).  B=2, S=2048, E=1024, H=16, D=64.
// Round 15 = round 13 resubmitted byte-identical (two prior attempts died to
// "container failed twice" with no pytest/compile output = infra, clustered
// with 178s acquires / 795s pushes this session; kernel re-audited clean:
// vmcnt ledger, OOB, rotation, barrier uniformity all verified).
// Round 13: round-11 proven base (passed @86us) with ONE structural change:
// attn q-tile 128 -> 64 (m=1 per wave), grid 1024 -> 2048 blocks, for TLP
// (round-11 occupancy was 26% with only 4 blocks/CU of work; now 8/CU work).
// Pipeline macro-structure identical: same 32-tile loop, unroll-4 + peeled
// tail, same WAIT vmcnt(2) (queue {S2,B2,S2} -> retire S(i)+B(i), leave
// S(i+1)). BLOAD is 2 loads (one bias row-set per wave).

typedef unsigned short ushort_t;
typedef __attribute__((ext_vector_type(8))) short bf16x8;
typedef __attribute__((ext_vector_type(4))) float floatx4;
typedef __attribute__((ext_vector_type(2))) unsigned int uintx2;

#define NB 2
#define NS 2048
#define NE 1024
#define NH 16
#define ND 64
#define LOG2E 1.44269504f

__device__ __forceinline__ unsigned short f2bf(float f) {
  unsigned int u = __float_as_uint(f);
  return (unsigned short)((u + 0x7fffu + ((u >> 16) & 1u)) >> 16);
}
__device__ __forceinline__ float bf2f(unsigned short h) {
  return __uint_as_float(((unsigned int)h) << 16);
}

__device__ __forceinline__ void gload_lds16(const void* g, void* l) {
  __builtin_amdgcn_global_load_lds(
      (const __attribute__((address_space(1))) unsigned int*)g,
      (__attribute__((address_space(3))) unsigned int*)l, 16, 0, 0);
}

// deterministic (asm) 8-byte global load: counted in vmcnt budgets.
__device__ __forceinline__ uintx2 gload8(const void* p) {
  uintx2 r;
  asm volatile("global_load_dwordx2 %0, %1, off"
               : "=v"(r) : "v"(p) : "memory");
  return r;
}

__device__ __forceinline__ float fexp2(float x) {
#if __has_builtin(__builtin_amdgcn_exp2f)
  return __builtin_amdgcn_exp2f(x);
#else
  return exp2f(x);
#endif
}

__device__ __forceinline__ unsigned int cvtpk_bf16(float lo, float hi) {
  unsigned int r;
  asm("v_cvt_pk_bf16_f32 %0, %1, %2" : "=v"(r) : "v"(lo), "v"(hi));
  return r;
}

__device__ __forceinline__ void pl32swap(unsigned int& a, unsigned int& b) {
#if __has_builtin(__builtin_amdgcn_permlane32_swap)
  uintx2 r = __builtin_amdgcn_permlane32_swap(a, b, false, false);
  a = r[0]; b = r[1];
#else
  asm("v_permlane32_swap_b32 %0, %1" : "+v"(a), "+v"(b));
#endif
}
__device__ __forceinline__ void pl16swap(unsigned int& a, unsigned int& b) {
#if __has_builtin(__builtin_amdgcn_permlane16_swap)
  uintx2 r = __builtin_amdgcn_permlane16_swap(a, b, false, false);
  a = r[0]; b = r[1];
#else
  asm("v_permlane16_swap_b32 %0, %1" : "+v"(a), "+v"(b));
#endif
}

// ---------------------------------------------------------------------------
// Kernel 1: fp32->bf16 conversions + fused (adj, mask) -> bias[b][q][k] bf16.
// Bias stored pre-scaled by log2(e).
// ---------------------------------------------------------------------------
__global__ __launch_bounds__(256) void convert_kernel(
    const float* __restrict__ q, const float* __restrict__ k, const float* __restrict__ v,
    const float* __restrict__ wq, const float* __restrict__ wk,
    const float* __restrict__ wv, const float* __restrict__ wo,
    const float* __restrict__ adj, const int* __restrict__ mask,
    ushort_t* __restrict__ qb, ushort_t* __restrict__ kb, ushort_t* __restrict__ vb,
    ushort_t* __restrict__ wqb, ushort_t* __restrict__ wkb,
    ushort_t* __restrict__ wvb, ushort_t* __restrict__ wob,
    ushort_t* __restrict__ bias)
{
  const long U1 = (long)NB * NS * NE / 8;  // 524288
  const long U2 = (long)NE * NE / 8;       // 131072
  long idx = (long)blockIdx.x * 256 + threadIdx.x;
  const float* src;
  ushort_t* dst;
  if (idx < U1) { src = q; dst = qb; }
  else if ((idx -= U1) < U1) { src = k; dst = kb; }
  else if ((idx -= U1) < U1) { src = v; dst = vb; }
  else if ((idx -= U1) < U2) { src = wq; dst = wqb; }
  else if ((idx -= U2) < U2) { src = wk; dst = wkb; }
  else if ((idx -= U2) < U2) { src = wv; dst = wvb; }
  else if ((idx -= U2) < U2) { src = wo; dst = wob; }
  else {
    idx -= U2;  // bias unit index in [0, B*S*S/8)
    long flat = idx * 8;
    long rem = flat & ((1L << 22) - 1);
    const float4* a4 = (const float4*)(adj + rem);
    const int4* m4 = (const int4*)(mask + flat);
    float4 a0 = a4[0], a1 = a4[1];
    int4 m0 = m4[0], m1 = m4[1];
    const float NEGV = -1e30f;
    union { ushort_t us[8]; uint4 v4; } o;
    o.us[0] = f2bf((m0.x ? a0.x : NEGV) * LOG2E);
    o.us[1] = f2bf((m0.y ? a0.y : NEGV) * LOG2E);
    o.us[2] = f2bf((m0.z ? a0.z : NEGV) * LOG2E);
    o.us[3] = f2bf((m0.w ? a0.w : NEGV) * LOG2E);
    o.us[4] = f2bf((m1.x ? a1.x : NEGV) * LOG2E);
    o.us[5] = f2bf((m1.y ? a1.y : NEGV) * LOG2E);
    o.us[6] = f2bf((m1.z ? a1.z : NEGV) * LOG2E);
    o.us[7] = f2bf((m1.w ? a1.w : NEGV) * LOG2E);
    ((uint4*)bias)[idx] = o.v4;
    return;
  }
  const float4* s4 = (const float4*)src;
  float4 a0 = s4[idx * 2], a1 = s4[idx * 2 + 1];
  union { ushort_t us[8]; uint4 v4; } o;
  o.us[0] = f2bf(a0.x); o.us[1] = f2bf(a0.y); o.us[2] = f2bf(a0.z); o.us[3] = f2bf(a0.w);
  o.us[4] = f2bf(a1.x); o.us[5] = f2bf(a1.y); o.us[6] = f2bf(a1.z); o.us[7] = f2bf(a1.w);
  ((uint4*)dst)[idx] = o.v4;
}

// ---------------------------------------------------------------------------
// Kernel 2: fused QKV projection GEMM, triple-buffered counted-vmcnt pipeline.
// (round-11 exact, scalar epilogue stores)
// ---------------------------------------------------------------------------
__global__ __launch_bounds__(256) void qkv_kernel(
    const ushort_t* __restrict__ xq, const ushort_t* __restrict__ xk, const ushort_t* __restrict__ xv,
    const ushort_t* __restrict__ wqb, const ushort_t* __restrict__ wkb, const ushort_t* __restrict__ wvb,
    const float* __restrict__ bq, const float* __restrict__ bk, const float* __restrict__ bvv,
    ushort_t* __restrict__ Qh, ushort_t* __restrict__ Kh, ushort_t* __restrict__ Vt)
{
  __shared__ __align__(16) ushort_t As[3][128 * 32];  // 24KB
  __shared__ __align__(16) ushort_t Bs[3][128 * 32];  // 24KB

  int z = blockIdx.z;
  const ushort_t* X = (z == 0) ? xq : (z == 1) ? xk : xv;
  const ushort_t* W = (z == 0) ? wqb : (z == 1) ? wkb : wvb;
  const float* bias = (z == 0) ? bq : (z == 1) ? bk : bvv;

  int t = threadIdx.x;
  int lane = t & 63, w = t >> 6;
  int quad = lane >> 4, l16 = lane & 15;
  int wr = w >> 1, wc = w & 1;
  int m0 = blockIdx.y * 128, f0 = blockIdx.x * 128;

  int arow = t >> 2, apart = t & 3;
  const ushort_t* Xg = X + (long)(m0 + arow) * NE + apart * 8;
  const ushort_t* Wg = W + (long)(f0 + arow) * NE + apart * 8;

  auto STAGE = [&](int kk, int buf) {
    int k0 = kk * 32;
    gload_lds16(Xg + k0, &As[buf][t * 8]);
    gload_lds16(Xg + k0 + 64 * NE, &As[buf][64 * 32 + t * 8]);
    gload_lds16(Wg + k0, &Bs[buf][t * 8]);
    gload_lds16(Wg + k0 + 64 * NE, &Bs[buf][64 * 32 + t * 8]);
  };
  STAGE(0, 0);
  STAGE(1, 1);

  floatx4 acc[4][4] = {};
  int b = 0;
  for (int k = 0; k < 32; ++k) {
    asm volatile("s_waitcnt vmcnt(4) lgkmcnt(0)" ::: "memory");
    __builtin_amdgcn_s_barrier();
    __builtin_amdgcn_sched_barrier(0);
    int nb = (b == 0) ? 2 : b - 1;
    STAGE((k + 2) & 31, nb);
    const ushort_t* Ab = As[b];
    const ushort_t* Bb = Bs[b];
    bf16x8 af[4], bf[4];
#pragma unroll
    for (int i = 0; i < 4; i++)
      af[i] = *(const bf16x8*)(Ab + (wr * 64 + i * 16 + l16) * 32 + quad * 8);
#pragma unroll
    for (int j = 0; j < 4; j++)
      bf[j] = *(const bf16x8*)(Bb + (wc * 64 + j * 16 + l16) * 32 + quad * 8);
#pragma unroll
    for (int i = 0; i < 4; i++)
#pragma unroll
      for (int j = 0; j < 4; j++)
        acc[i][j] = __builtin_amdgcn_mfma_f32_16x16x32_bf16(af[i], bf[j], acc[i][j], 0, 0, 0);
    b = (b == 2) ? 0 : b + 1;
  }
  asm volatile("s_waitcnt vmcnt(0)" ::: "memory");

  ushort_t* Out = (z == 0) ? Qh : (z == 1) ? Kh : Vt;
  bool isV = (z == 2);
#pragma unroll
  for (int j = 0; j < 4; j++) {
    int f = f0 + wc * 64 + j * 16 + l16;
    float bval = bias[f];
    int h = f >> 6, d = f & 63;
#pragma unroll
    for (int i = 0; i < 4; i++) {
      int mbase = m0 + wr * 64 + i * 16 + quad * 4;
#pragma unroll
      for (int r = 0; r < 4; r++) {
        int m = mbase + r;
        int bb2 = m >> 11, s = m & 2047;
        float y = acc[i][j][r] + bval;
        long off;
        if (!isV) off = ((long)(bb2 * NH + h) * NS + s) * ND + d;     // [B,H,S,D]
        else      off = ((long)(bb2 * NH + h) * ND + d) * NS + s;     // [B,H,D,S]
        Out[off] = f2bf(y);
      }
    }
  }
}

// ---------------------------------------------------------------------------
// Kernel 3: block-k-split flash attention, q-tile 64 (m=1 per wave), TLP 2x.
// Block 256 (4 waves), wave w owns q rows w*16..w*16+15. ks=2 k-halves of
// 1024, 32 k-tiles of 32. 4-deep K/V LDS buffers (32KB), counted pipeline
// identical to round 11: per iter ONE s_waitcnt vmcnt(2) lgkmcnt(0) + ONE
// barrier; queue {S(i)2, B(i)2, S(i+1)2} -> wait retires {S(i), B(i)},
// leaves S(i+1). Unroll-by-4, static buffers + static bcA/bcB, peeled tail.
// Swapped QK^T + in-register P (cvt_pk + permlane), proven math.
// Grid 2048 = (32qt, 32bh, 2ks) -> 8 blocks/CU of work (round 11 had 4).
// Epilogue: self-normalized bf16 O-partial + f32 partial lsum per row.
// ---------------------------------------------------------------------------
__global__ __launch_bounds__(256, 3) void attn_kernel(
    const ushort_t* __restrict__ Qh, const ushort_t* __restrict__ Kh,
    const ushort_t* __restrict__ Vt, const ushort_t* __restrict__ bias,
    ushort_t* __restrict__ PO, float* __restrict__ L)
{
  __shared__ __align__(16) ushort_t KVs[4][4096];  // [buf][K 2048 | V 2048] 32KB

  int t = threadIdx.x, lane = t & 63, w = t >> 6;
  int quad = lane >> 4, l16 = lane & 15;
  // XCD swizzle: 2048 blocks, 256 consecutive wg per XCD (16-head bias
  // groups co-located; neutral-verified for perf, kept for determinism).
  int orig = blockIdx.x;
  int wg = ((orig & 7) << 8) | (orig >> 3);
  int h = wg & 15, g = wg >> 4;                 // g in [0,128)
  int ks = g & 1, qt = (g >> 1) & 31, bsel = g >> 6;
  int bh = bsel * NH + h;
  int q0 = qt * 64;
  int kbase = ks * (NS / 2);

  const ushort_t* Qg = Qh + ((long)bh * NS + q0) * ND;
  const ushort_t* Kg = Kh + ((long)bh * NS + kbase) * ND;
  const ushort_t* Vg = Vt + (long)bh * ND * NS + kbase;
  const ushort_t* biasg = bias + (long)bsel * NS * NS;

  // Q fragments straight from global (one-time). Wave w owns rows w*16..+15.
  bf16x8 aq[2];
#pragma unroll
  for (int kd = 0; kd < 2; kd++)
    aq[kd] = *(const bf16x8*)(Qg + (long)(w * 16 + l16) * ND + kd * 32 + quad * 8);

  // staging sources (XOR-swizzled dest layouts, round-7/9/11 proven)
  int krow = t >> 3, kc = (t & 7) ^ (krow & 7);
  int vsr = t >> 3, vc2 = (t & 7) ^ (vsr & 7);
  int vrow = vsr * 2 + (vc2 >> 2), vpart = vc2 & 3;
  const ushort_t* Kgp = Kg + (long)krow * ND + kc * 8;    // + tile*32*ND
  const ushort_t* Vgp = Vg + (long)vrow * NS + vpart * 8; // + tile*32
  const ushort_t* pB0 = biasg + (long)(q0 + w * 16 + l16) * NS + kbase + quad * 4;

  auto STAGE = [&](int tile, int buf) {  // 2 gload_lds per wave
    int k0 = tile * 32;
    gload_lds16(Kgp + (long)k0 * ND, &KVs[buf][t * 8]);
    gload_lds16(Vgp + k0, &KVs[buf][2048 + t * 8]);
  };
  uintx2 bcA[2], bcB[2];
  auto BLOAD = [&](uintx2 (&dst)[2], int tile) {  // 2 asm loads per wave
    long off = (long)tile * 32;
    dst[0] = gload8(pB0 + off);
    dst[1] = gload8(pB0 + off + 16);
  };

  floatx4 acc[4] = {};
  float lsum = 0.f;
  const int ks_x = l16 & 7;
  const int vs_c = (((l16 & 1) * 4 + quad) ^ (l16 >> 1)) * 8;

  auto BODY = [&](const ushort_t* Kb, const ushort_t* Vb,
                  const uintx2 (&bcv)[2]) {
    bf16x8 bk[2][2], bv[4];
#pragma unroll
    for (int jk = 0; jk < 2; jk++)
#pragma unroll
      for (int kd = 0; kd < 2; kd++)
        bk[jk][kd] = *(const bf16x8*)(Kb + (jk * 16 + l16) * 64
                                         + ((kd * 4 + quad) ^ ks_x) * 8);
#pragma unroll
    for (int j = 0; j < 4; j++)
      bv[j] = *(const bf16x8*)(Vb + (j * 8 + (l16 >> 1)) * 64 + vs_c);

    floatx4 sc[2] = {};
#pragma unroll
    for (int jk = 0; jk < 2; jk++)
#pragma unroll
      for (int kd = 0; kd < 2; kd++)
        sc[jk] = __builtin_amdgcn_mfma_f32_16x16x32_bf16(bk[jk][kd], aq[kd], sc[jk], 0, 0, 0);
    float p[2][4];
#pragma unroll
    for (int jk = 0; jk < 2; jk++) {
      unsigned int d0 = bcv[jk][0], d1 = bcv[jk][1];
      float b0 = __uint_as_float(d0 << 16);
      float b1 = __uint_as_float(d0 & 0xffff0000u);
      float b2 = __uint_as_float(d1 << 16);
      float b3 = __uint_as_float(d1 & 0xffff0000u);
      p[jk][0] = fexp2(fmaf(sc[jk][0], 0.125f * LOG2E, b0));
      p[jk][1] = fexp2(fmaf(sc[jk][1], 0.125f * LOG2E, b1));
      p[jk][2] = fexp2(fmaf(sc[jk][2], 0.125f * LOG2E, b2));
      p[jk][3] = fexp2(fmaf(sc[jk][3], 0.125f * LOG2E, b3));
    }
    lsum += ((p[0][0] + p[0][1]) + (p[0][2] + p[0][3]))
          + ((p[1][0] + p[1][1]) + (p[1][2] + p[1][3]));
    unsigned int A0 = cvtpk_bf16(p[0][0], p[0][1]);
    unsigned int A1 = cvtpk_bf16(p[0][2], p[0][3]);
    unsigned int B0 = cvtpk_bf16(p[1][0], p[1][1]);
    unsigned int B1 = cvtpk_bf16(p[1][2], p[1][3]);
    pl32swap(A0, B0); pl16swap(A0, B0);
    pl32swap(A1, B1); pl16swap(A1, B1);
    union { unsigned int u[4]; bf16x8 v8; } pf;
    pf.u[0] = A0; pf.u[1] = A1; pf.u[2] = B0; pf.u[3] = B1;
#pragma unroll
    for (int j = 0; j < 4; j++)
      acc[j] = __builtin_amdgcn_mfma_f32_16x16x32_bf16(pf.v8, bv[j], acc[j], 0, 0, 0);
  };

#define SB() __builtin_amdgcn_sched_barrier(0)
#define WAIT2()                                                   \
  asm volatile("s_waitcnt vmcnt(2) lgkmcnt(0)" ::: "memory");     \
  __builtin_amdgcn_s_barrier();                                   \
  SB()

  // prologue: drain compiler loads (aq), then establish queue [S0, B0, S1]
  SB();
  asm volatile("s_waitcnt vmcnt(0)" ::: "memory");
  SB();
  STAGE(0, 0); SB();
  BLOAD(bcA, 0); SB();
  STAGE(1, 1); SB();

#pragma unroll 1
  for (int ii = 0; ii < 7; ++ii) {
    int base = ii * 4;
    WAIT2(); BLOAD(bcB, base + 1); SB(); STAGE(base + 2, 2); SB();
    BODY(&KVs[0][0], &KVs[0][2048], bcA);
    WAIT2(); BLOAD(bcA, base + 2); SB(); STAGE(base + 3, 3); SB();
    BODY(&KVs[1][0], &KVs[1][2048], bcB);
    WAIT2(); BLOAD(bcB, base + 3); SB(); STAGE(base + 4, 0); SB();
    BODY(&KVs[2][0], &KVs[2][2048], bcA);
    WAIT2(); BLOAD(bcA, base + 4); SB(); STAGE(base + 5, 1); SB();
    BODY(&KVs[3][0], &KVs[3][2048], bcB);
  }
  // peeled i = 28..31
  WAIT2(); BLOAD(bcB, 29); SB(); STAGE(30, 2); SB();
  BODY(&KVs[0][0], &KVs[0][2048], bcA);
  WAIT2(); BLOAD(bcA, 30); SB(); STAGE(31, 3); SB();
  BODY(&KVs[1][0], &KVs[1][2048], bcB);
  WAIT2(); BLOAD(bcB, 31); SB();
  BODY(&KVs[2][0], &KVs[2][2048], bcA);
  asm volatile("s_waitcnt vmcnt(0) lgkmcnt(0)" ::: "memory");
  __builtin_amdgcn_s_barrier();
  SB();
  BODY(&KVs[3][0], &KVs[3][2048], bcB);

#undef WAIT2
#undef SB

  // partial row-sum: reduce across quads -> every lane holds sum for q=l16
  {
    float s = lsum;
    s += __shfl_xor(s, 16);
    s += __shfl_xor(s, 32);
    lsum = s;
  }

  // epilogue: self-normalized bf16 partial O + f32 partial lsum.
  // PO flat layout: [ks][bh*2048 + qglobal][64d], qglobal = qt*64 + row.
  ushort_t* pog = PO + (long)ks * 4194304 + (long)bh * 131072 + qt * 4096;
  float* Lg = L + ks * 65536 + bh * 2048 + qt * 64;
#pragma unroll
  for (int r = 0; r < 4; r++) {
    float inv = 1.0f / __shfl(lsum, quad * 4 + r);
    int row = w * 16 + quad * 4 + r;
#pragma unroll
    for (int j = 0; j < 4; j++)
      pog[row * 64 + j * 16 + l16] = f2bf(acc[j][r] * inv);
  }
  if (quad == 0) Lg[w * 16 + l16] = lsum;
}

// ---------------------------------------------------------------------------
// Kernel 3b: combine the two k-half partials.
// O = (l0*O0n + l1*O1n) / (l0+l1).  ~25MB traffic, memory-bound.
// ---------------------------------------------------------------------------
__global__ __launch_bounds__(256) void combine_kernel(
    const ushort_t* __restrict__ PO, const float* __restrict__ L,
    ushort_t* __restrict__ aout)
{
  int idx = blockIdx.x * 256 + threadIdx.x;   // [0, 524288)
  long f = (long)idx * 8;
  int r = (int)(f >> 6);                      // row id [0, 65536) = bh*2048+q
  float l0 = L[r], l1 = L[65536 + r];
  float inv = 1.0f / (l0 + l1);
  float w0 = l0 * inv, w1 = l1 * inv;
  union { uint4 v4; ushort_t us[8]; } ua, ub, o;
  ua.v4 = ((const uint4*)PO)[idx];
  ub.v4 = ((const uint4*)(PO + 4194304))[idx];
#pragma unroll
  for (int j = 0; j < 8; j++)
    o.us[j] = f2bf(w0 * bf2f(ua.us[j]) + w1 * bf2f(ub.us[j]));
  int q = r & 2047, bh = r >> 11;
  int b_ = bh >> 4, h = bh & 15, d0 = (int)(f & 63);
  long off = (long)(b_ * NS + q) * NE + h * ND + d0;
  *(uint4*)(aout + off) = o.v4;
}

// ---------------------------------------------------------------------------
// Kernel 4: output projection, triple-buffered counted-vmcnt pipeline.
// ---------------------------------------------------------------------------
__global__ __launch_bounds__(256) void oproj_kernel(
    const ushort_t* __restrict__ A, const ushort_t* __restrict__ Wob,
    const float* __restrict__ bo, float* __restrict__ out)
{
  __shared__ __align__(16) ushort_t As[3][128 * 32];  // 24KB
  __shared__ __align__(16) ushort_t Bs[3][64 * 32];   // 12KB

  int t = threadIdx.x;
  int lane = t & 63, w = t >> 6;
  int quad = lane >> 4, l16 = lane & 15;
  int wr = w >> 1, wc = w & 1;
  int m0 = blockIdx.y * 128, f0 = blockIdx.x * 64;

  int arow = t >> 2, apart = t & 3;
  const ushort_t* Xg = A + (long)(m0 + arow) * NE + apart * 8;
  const ushort_t* Wg = Wob + (long)(f0 + arow) * NE + apart * 8;

  auto STAGE = [&](int kk, int buf) {
    int k0 = kk * 32;
    gload_lds16(Xg + k0, &As[buf][t * 8]);
    gload_lds16(Xg + k0 + 64 * NE, &As[buf][64 * 32 + t * 8]);
    gload_lds16(Wg + k0, &Bs[buf][t * 8]);
  };
  STAGE(0, 0);
  STAGE(1, 1);

  floatx4 acc[4][2] = {};
  int b = 0;
  for (int k = 0; k < 32; ++k) {
    asm volatile("s_waitcnt vmcnt(3) lgkmcnt(0)" ::: "memory");
    __builtin_amdgcn_s_barrier();
    __builtin_amdgcn_sched_barrier(0);
    int nb = (b == 0) ? 2 : b - 1;
    STAGE((k + 2) & 31, nb);
    const ushort_t* Ab = As[b];
    const ushort_t* Bb = Bs[b];
    bf16x8 af[4], bf[2];
#pragma unroll
    for (int i = 0; i < 4; i++)
      af[i] = *(const bf16x8*)(Ab + (wr * 64 + i * 16 + l16) * 32 + quad * 8);
#pragma unroll
    for (int j = 0; j < 2; j++)
      bf[j] = *(const bf16x8*)(Bb + (wc * 32 + j * 16 + l16) * 32 + quad * 8);
#pragma unroll
    for (int i = 0; i < 4; i++)
#pragma unroll
      for (int j = 0; j < 2; j++)
        acc[i][j] = __builtin_amdgcn_mfma_f32_16x16x32_bf16(af[i], bf[j], acc[i][j], 0, 0, 0);
    b = (b == 2) ? 0 : b + 1;
  }
  asm volatile("s_waitcnt vmcnt(0)" ::: "memory");

#pragma unroll
  for (int j = 0; j < 2; j++) {
    int f = f0 + wc * 32 + j * 16 + l16;
    float bval = bo[f];
#pragma unroll
    for (int i = 0; i < 4; i++) {
      int mbase = m0 + wr * 64 + i * 16 + quad * 4;
#pragma unroll
      for (int r = 0; r < 4; r++) {
        int m = mbase + r;
        out[(long)m * NE + f] = acc[i][j][r] + bval;
      }
    }
  }
}

// ---------------------------------------------------------------------------
extern "C" void kernel_launch(void* const* d_in, const int* in_sizes, int n_in,
                              void* d_out, int out_size, void* d_ws, size_t ws_size,
                              hipStream_t stream) {
  const float* query = (const float*)d_in[0];
  const float* key   = (const float*)d_in[1];
  const float* value = (const float*)d_in[2];
  const float* adj   = (const float*)d_in[3];
  const int*   mask  = (const int*)d_in[4];
  const float* Wq = (const float*)d_in[5];
  const float* bq = (const float*)d_in[6];
  const float* Wk = (const float*)d_in[7];
  const float* bk = (const float*)d_in[8];
  const float* Wv = (const float*)d_in[9];
  const float* bv = (const float*)d_in[10];
  const float* Wo = (const float*)d_in[11];
  const float* bo = (const float*)d_in[12];
  float* out = (float*)d_out;

  char* ws = (char*)d_ws;
  const size_t MB = 1ull << 20;
  ushort_t* qb   = (ushort_t*)(ws + 0 * MB);    // 8 MiB  [B*S, E] bf16 (dead after qkv)
  ushort_t* kb   = (ushort_t*)(ws + 8 * MB);    // 8 MiB  (dead after qkv)
  ushort_t* vb   = (ushort_t*)(ws + 16 * MB);   // 8 MiB  (dead after qkv)
  ushort_t* wqb  = (ushort_t*)(ws + 24 * MB);   // 2 MiB
  ushort_t* wkb  = (ushort_t*)(ws + 26 * MB);   // 2 MiB
  ushort_t* wvb  = (ushort_t*)(ws + 28 * MB);   // 2 MiB
  ushort_t* wob  = (ushort_t*)(ws + 30 * MB);   // 2 MiB (live until oproj)
  ushort_t* Qh   = (ushort_t*)(ws + 32 * MB);   // 8 MiB  [B,H,S,D]
  ushort_t* Kh   = (ushort_t*)(ws + 40 * MB);   // 8 MiB  [B,H,S,D]
  ushort_t* Vt   = (ushort_t*)(ws + 48 * MB);   // 8 MiB  [B,H,D,S]
  ushort_t* aout = (ushort_t*)(ws + 56 * MB);   // 8 MiB  [B,S,E]
  ushort_t* bias = (ushort_t*)(ws + 64 * MB);   // 16 MiB [B,S,S] (pre-scaled by log2e)
  // attn partials overlay the dead qb/kb/vb region:
  ushort_t* PO   = (ushort_t*)(ws + 0 * MB);    // 16 MiB: 2 x [32bh, 2048q, 64d] bf16
  float*    Lp   = (float*)(ws + 16 * MB);      // 512 KiB: 2 x 65536 f32

  convert_kernel<<<12288, 256, 0, stream>>>(query, key, value, Wq, Wk, Wv, Wo,
                                            adj, mask, qb, kb, vb, wqb, wkb, wvb, wob, bias);
  qkv_kernel<<<dim3(8, 32, 3), 256, 0, stream>>>(qb, kb, vb, wqb, wkb, wvb,
                                                 bq, bk, bv, Qh, Kh, Vt);
  attn_kernel<<<dim3(2048), 256, 0, stream>>>(Qh, Kh, Vt, bias, PO, Lp);
  combine_kernel<<<dim3(2048), 256, 0, stream>>>(PO, Lp, aout);
  oproj_kernel<<<dim3(16, 32), 256, 0, stream>>>(aout, wob, bo, out);
}

// Round 10
// 292.837 us; speedup vs baseline: 1.1022x; 1.1022x over previous
//
#include <hip/hip_runtime.h>

// GraphAttention on MI355X (gfx950).  B=2, S=2048, E=1024, H=16, D=64.
// Round 16: round-11 base (q-tile 128, best measured @86us) with the bias
// path restructured from scattered 8B gathers (4 instr x 16 cache-lines per
// wave-iter = the measured ~2000-cycle/iter fixed overhead) to a COALESCED
// staged stream: convert writes biasT[b][k-tile][q][32k] with the read-side
// XOR swizzle pre-baked; attn stages the 8KB bias tile per iteration with
// global_load_lds (2/thread) alongside K/V and reads per-lane values via
// ds_read_b64. vmcnt ledger simplifies to {S(i)4, S(i+1)4}, wait vmcnt(4),
// 3-deep 16KB buffers (48KB LDS). No asm gathers remain in the loop.
// qkv/oproj/combine/epilogue identical to round 11.

typedef unsigned short ushort_t;
typedef __attribute__((ext_vector_type(8))) short bf16x8;
typedef __attribute__((ext_vector_type(4))) float floatx4;
typedef __attribute__((ext_vector_type(2))) unsigned int uintx2;

#define NB 2
#define NS 2048
#define NE 1024
#define NH 16
#define ND 64
#define LOG2E 1.44269504f

__device__ __forceinline__ unsigned short f2bf(float f) {
  unsigned int u = __float_as_uint(f);
  return (unsigned short)((u + 0x7fffu + ((u >> 16) & 1u)) >> 16);
}
__device__ __forceinline__ float bf2f(unsigned short h) {
  return __uint_as_float(((unsigned int)h) << 16);
}

__device__ __forceinline__ void gload_lds16(const void* g, void* l) {
  __builtin_amdgcn_global_load_lds(
      (const __attribute__((address_space(1))) unsigned int*)g,
      (__attribute__((address_space(3))) unsigned int*)l, 16, 0, 0);
}

__device__ __forceinline__ float fexp2(float x) {
#if __has_builtin(__builtin_amdgcn_exp2f)
  return __builtin_amdgcn_exp2f(x);
#else
  return exp2f(x);
#endif
}

__device__ __forceinline__ unsigned int cvtpk_bf16(float lo, float hi) {
  unsigned int r;
  asm("v_cvt_pk_bf16_f32 %0, %1, %2" : "=v"(r) : "v"(lo), "v"(hi));
  return r;
}

__device__ __forceinline__ void pl32swap(unsigned int& a, unsigned int& b) {
#if __has_builtin(__builtin_amdgcn_permlane32_swap)
  uintx2 r = __builtin_amdgcn_permlane32_swap(a, b, false, false);
  a = r[0]; b = r[1];
#else
  asm("v_permlane32_swap_b32 %0, %1" : "+v"(a), "+v"(b));
#endif
}
__device__ __forceinline__ void pl16swap(unsigned int& a, unsigned int& b) {
#if __has_builtin(__builtin_amdgcn_permlane16_swap)
  uintx2 r = __builtin_amdgcn_permlane16_swap(a, b, false, false);
  a = r[0]; b = r[1];
#else
  asm("v_permlane16_swap_b32 %0, %1" : "+v"(a), "+v"(b));
#endif
}

// ---------------------------------------------------------------------------
// Kernel 1: fp32->bf16 conversions + fused (adj, mask) -> biasT bf16.
// biasT layout: [b][kt=k/32][q][4 chunks of 8 cols], chunk at position c'
// holds source cols kt*32 + (c'^((q>>1)&3))*8 .. +8, pre-scaled by log2(e).
// (read-side LDS swizzle baked into the global layout)
// ---------------------------------------------------------------------------
__global__ __launch_bounds__(256) void convert_kernel(
    const float* __restrict__ q, const float* __restrict__ k, const float* __restrict__ v,
    const float* __restrict__ wq, const float* __restrict__ wk,
    const float* __restrict__ wv, const float* __restrict__ wo,
    const float* __restrict__ adj, const int* __restrict__ mask,
    ushort_t* __restrict__ qb, ushort_t* __restrict__ kb, ushort_t* __restrict__ vb,
    ushort_t* __restrict__ wqb, ushort_t* __restrict__ wkb,
    ushort_t* __restrict__ wvb, ushort_t* __restrict__ wob,
    ushort_t* __restrict__ bias)
{
  const long U1 = (long)NB * NS * NE / 8;  // 524288
  const long U2 = (long)NE * NE / 8;       // 131072
  long idx = (long)blockIdx.x * 256 + threadIdx.x;
  const float* src;
  ushort_t* dst;
  if (idx < U1) { src = q; dst = qb; }
  else if ((idx -= U1) < U1) { src = k; dst = kb; }
  else if ((idx -= U1) < U1) { src = v; dst = vb; }
  else if ((idx -= U1) < U2) { src = wq; dst = wqb; }
  else if ((idx -= U2) < U2) { src = wk; dst = wkb; }
  else if ((idx -= U2) < U2) { src = wv; dst = wvb; }
  else if ((idx -= U2) < U2) { src = wo; dst = wob; }
  else {
    idx -= U2;  // biasT chunk index u in [0, B*S*S/8) = [0, 1048576)
    long u = idx;
    int cp = (int)(u & 3);
    int qq = (int)((u >> 2) & 2047);
    int kt = (int)((u >> 13) & 63);
    int b_ = (int)(u >> 19);
    int lc = cp ^ ((qq >> 1) & 3);
    int k0 = kt * 32 + lc * 8;
    const float4* a4 = (const float4*)(adj + (long)qq * NS + k0);
    const int4* m4 = (const int4*)(mask + (long)b_ * NS * NS + (long)qq * NS + k0);
    float4 a0 = a4[0], a1 = a4[1];
    int4 m0 = m4[0], m1 = m4[1];
    const float NEGV = -1e30f;
    union { ushort_t us[8]; uint4 v4; } o;
    o.us[0] = f2bf((m0.x ? a0.x : NEGV) * LOG2E);
    o.us[1] = f2bf((m0.y ? a0.y : NEGV) * LOG2E);
    o.us[2] = f2bf((m0.z ? a0.z : NEGV) * LOG2E);
    o.us[3] = f2bf((m0.w ? a0.w : NEGV) * LOG2E);
    o.us[4] = f2bf((m1.x ? a1.x : NEGV) * LOG2E);
    o.us[5] = f2bf((m1.y ? a1.y : NEGV) * LOG2E);
    o.us[6] = f2bf((m1.z ? a1.z : NEGV) * LOG2E);
    o.us[7] = f2bf((m1.w ? a1.w : NEGV) * LOG2E);
    ((uint4*)bias)[u] = o.v4;
    return;
  }
  const float4* s4 = (const float4*)src;
  float4 a0 = s4[idx * 2], a1 = s4[idx * 2 + 1];
  union { ushort_t us[8]; uint4 v4; } o;
  o.us[0] = f2bf(a0.x); o.us[1] = f2bf(a0.y); o.us[2] = f2bf(a0.z); o.us[3] = f2bf(a0.w);
  o.us[4] = f2bf(a1.x); o.us[5] = f2bf(a1.y); o.us[6] = f2bf(a1.z); o.us[7] = f2bf(a1.w);
  ((uint4*)dst)[idx] = o.v4;
}

// ---------------------------------------------------------------------------
// Kernel 2: fused QKV projection GEMM, triple-buffered counted-vmcnt pipeline.
// (round-11 exact)
// ---------------------------------------------------------------------------
__global__ __launch_bounds__(256) void qkv_kernel(
    const ushort_t* __restrict__ xq, const ushort_t* __restrict__ xk, const ushort_t* __restrict__ xv,
    const ushort_t* __restrict__ wqb, const ushort_t* __restrict__ wkb, const ushort_t* __restrict__ wvb,
    const float* __restrict__ bq, const float* __restrict__ bk, const float* __restrict__ bvv,
    ushort_t* __restrict__ Qh, ushort_t* __restrict__ Kh, ushort_t* __restrict__ Vt)
{
  __shared__ __align__(16) ushort_t As[3][128 * 32];  // 24KB
  __shared__ __align__(16) ushort_t Bs[3][128 * 32];  // 24KB

  int z = blockIdx.z;
  const ushort_t* X = (z == 0) ? xq : (z == 1) ? xk : xv;
  const ushort_t* W = (z == 0) ? wqb : (z == 1) ? wkb : wvb;
  const float* bias = (z == 0) ? bq : (z == 1) ? bk : bvv;

  int t = threadIdx.x;
  int lane = t & 63, w = t >> 6;
  int quad = lane >> 4, l16 = lane & 15;
  int wr = w >> 1, wc = w & 1;
  int m0 = blockIdx.y * 128, f0 = blockIdx.x * 128;

  int arow = t >> 2, apart = t & 3;
  const ushort_t* Xg = X + (long)(m0 + arow) * NE + apart * 8;
  const ushort_t* Wg = W + (long)(f0 + arow) * NE + apart * 8;

  auto STAGE = [&](int kk, int buf) {
    int k0 = kk * 32;
    gload_lds16(Xg + k0, &As[buf][t * 8]);
    gload_lds16(Xg + k0 + 64 * NE, &As[buf][64 * 32 + t * 8]);
    gload_lds16(Wg + k0, &Bs[buf][t * 8]);
    gload_lds16(Wg + k0 + 64 * NE, &Bs[buf][64 * 32 + t * 8]);
  };
  STAGE(0, 0);
  STAGE(1, 1);

  floatx4 acc[4][4] = {};
  int b = 0;
  for (int k = 0; k < 32; ++k) {
    asm volatile("s_waitcnt vmcnt(4) lgkmcnt(0)" ::: "memory");
    __builtin_amdgcn_s_barrier();
    __builtin_amdgcn_sched_barrier(0);
    int nb = (b == 0) ? 2 : b - 1;
    STAGE((k + 2) & 31, nb);
    const ushort_t* Ab = As[b];
    const ushort_t* Bb = Bs[b];
    bf16x8 af[4], bf[4];
#pragma unroll
    for (int i = 0; i < 4; i++)
      af[i] = *(const bf16x8*)(Ab + (wr * 64 + i * 16 + l16) * 32 + quad * 8);
#pragma unroll
    for (int j = 0; j < 4; j++)
      bf[j] = *(const bf16x8*)(Bb + (wc * 64 + j * 16 + l16) * 32 + quad * 8);
#pragma unroll
    for (int i = 0; i < 4; i++)
#pragma unroll
      for (int j = 0; j < 4; j++)
        acc[i][j] = __builtin_amdgcn_mfma_f32_16x16x32_bf16(af[i], bf[j], acc[i][j], 0, 0, 0);
    b = (b == 2) ? 0 : b + 1;
  }
  asm volatile("s_waitcnt vmcnt(0)" ::: "memory");

  ushort_t* Out = (z == 0) ? Qh : (z == 1) ? Kh : Vt;
  bool isV = (z == 2);
#pragma unroll
  for (int j = 0; j < 4; j++) {
    int f = f0 + wc * 64 + j * 16 + l16;
    float bval = bias[f];
    int h = f >> 6, d = f & 63;
#pragma unroll
    for (int i = 0; i < 4; i++) {
      int mbase = m0 + wr * 64 + i * 16 + quad * 4;
#pragma unroll
      for (int r = 0; r < 4; r++) {
        int m = mbase + r;
        int bb2 = m >> 11, s = m & 2047;
        float y = acc[i][j][r] + bval;
        long off;
        if (!isV) off = ((long)(bb2 * NH + h) * NS + s) * ND + d;     // [B,H,S,D]
        else      off = ((long)(bb2 * NH + h) * ND + d) * NS + s;     // [B,H,D,S]
        Out[off] = f2bf(y);
      }
    }
  }
}

// ---------------------------------------------------------------------------
// Kernel 3: block-k-split flash attention, coalesced bias staging.
// Block 256 (4 waves), q-tile 128 (m=2/wave), ks=2 halves, 32 k-tiles of 32.
// 3-deep LDS buffers of 16KB = [K 4KB | V 4KB | biasT 8KB] (48KB total).
// STAGE = 4 gload_lds/thread (K 1, V 1, bias 2). Queue {S(i)4, S(i+1)4};
// per iter ONE s_waitcnt vmcnt(4) lgkmcnt(0) + ONE barrier retires S(i),
// leaves S(i+1) in flight; then STAGE(i+2) into buf (i+2)%3 (reads of that
// buffer finished in iter i-1). Unroll-3, fully static buffers, clean tail
// (no garbage loads). Bias values read per-lane via ds_read_b64 from the
// pre-swizzled staged tile. Swapped QK^T + in-register P (cvt_pk+permlane).
// Epilogue: self-normalized bf16 O-partial + f32 partial lsum (round-11).
// ---------------------------------------------------------------------------
__global__ __launch_bounds__(256, 3) void attn_kernel(
    const ushort_t* __restrict__ Qh, const ushort_t* __restrict__ Kh,
    const ushort_t* __restrict__ Vt, const ushort_t* __restrict__ bias,
    ushort_t* __restrict__ PO, float* __restrict__ L)
{
  __shared__ __align__(16) ushort_t KVs[3][8192];  // [buf][K 2048 | V 2048 | B 4096] shorts

  int t = threadIdx.x, lane = t & 63, w = t >> 6;
  int quad = lane >> 4, l16 = lane & 15;
  // XCD swizzle (1024 blocks): 16 head-blocks sharing a bias tile per XCD.
  int orig = blockIdx.x;
  int wg = ((orig & 7) << 7) | (orig >> 3);
  int h = wg & 15, g = wg >> 4;
  int ks = g & 1, qt = (g >> 1) & 15, bsel = g >> 5;
  int bh = bsel * NH + h;
  int q0 = qt * 128;
  int kbase = ks * (NS / 2);

  const ushort_t* Qg = Qh + ((long)bh * NS + q0) * ND;
  const ushort_t* Kg = Kh + ((long)bh * NS + kbase) * ND;
  const ushort_t* Vg = Vt + (long)bh * ND * NS + kbase;
  // biasT tile base for this block: [bsel][kt = ks*32 + i][q0..q0+128)[32k]
  const ushort_t* Bg = bias + (((long)(bsel * 64 + ks * 32) * NS + q0) * 32);

  // Q fragments straight from global (one-time).
  bf16x8 aq[2][2];
#pragma unroll
  for (int m = 0; m < 2; m++)
#pragma unroll
    for (int kd = 0; kd < 2; kd++)
      aq[m][kd] = *(const bf16x8*)(Qg + (long)(w * 32 + m * 16 + l16) * ND
                                      + kd * 32 + quad * 8);

  // K/V staging sources (XOR-swizzled dest layouts, round-7/9/11 proven)
  int krow = t >> 3, kc = (t & 7) ^ (krow & 7);
  int vsr = t >> 3, vc2 = (t & 7) ^ (vsr & 7);
  int vrow = vsr * 2 + (vc2 >> 2), vpart = vc2 & 3;
  const ushort_t* Kgp = Kg + (long)krow * ND + kc * 8;    // + tile*32*ND
  const ushort_t* Vgp = Vg + (long)vrow * NS + vpart * 8; // + tile*32
  const ushort_t* Bgp = Bg + t * 8;                        // + tile*65536

  auto STAGE = [&](int tile, int buf) {  // 4 gload_lds per thread/wave
    int k0 = tile * 32;
    gload_lds16(Kgp + (long)k0 * ND, &KVs[buf][t * 8]);
    gload_lds16(Vgp + k0, &KVs[buf][2048 + t * 8]);
    const ushort_t* bsrc = Bgp + (long)tile * 65536;
    gload_lds16(bsrc, &KVs[buf][4096 + t * 8]);
    gload_lds16(bsrc + 2048, &KVs[buf][4096 + 2048 + t * 8]);
  };

  floatx4 acc[2][4] = {};
  float lsum[2] = {0.f, 0.f};
  const int ks_x = l16 & 7;
  const int vs_c = (((l16 & 1) * 4 + quad) ^ (l16 >> 1)) * 8;

  auto BODY = [&](int buf) {
    const ushort_t* Kb = &KVs[buf][0];
    const ushort_t* Vb = &KVs[buf][2048];
    const ushort_t* Bb = &KVs[buf][4096];
    bf16x8 bk[2][2], bv[4];
#pragma unroll
    for (int jk = 0; jk < 2; jk++)
#pragma unroll
      for (int kd = 0; kd < 2; kd++)
        bk[jk][kd] = *(const bf16x8*)(Kb + (jk * 16 + l16) * 64
                                         + ((kd * 4 + quad) ^ ks_x) * 8);
#pragma unroll
    for (int j = 0; j < 4; j++)
      bv[j] = *(const bf16x8*)(Vb + (j * 8 + (l16 >> 1)) * 64 + vs_c);
#pragma unroll
    for (int m = 0; m < 2; m++) {
      floatx4 sc[2] = {};
#pragma unroll
      for (int jk = 0; jk < 2; jk++)
#pragma unroll
        for (int kd = 0; kd < 2; kd++)
          sc[jk] = __builtin_amdgcn_mfma_f32_16x16x32_bf16(bk[jk][kd], aq[m][kd], sc[jk], 0, 0, 0);
      // bias from staged pre-swizzled tile: row qq, cols jk*16 + quad*4 + r
      int qq = w * 32 + m * 16 + l16;
      int px = (qq >> 1) & 3;
      int hb = (quad & 1) * 4;
      uintx2 d0v = *(const uintx2*)(Bb + qq * 32 + (((quad >> 1) ^ px) * 8) + hb);
      uintx2 d1v = *(const uintx2*)(Bb + qq * 32 + (((2 + (quad >> 1)) ^ px) * 8) + hb);
      float p[2][4];
#pragma unroll
      for (int jk = 0; jk < 2; jk++) {
        unsigned int e0 = (jk == 0) ? d0v[0] : d1v[0];
        unsigned int e1 = (jk == 0) ? d0v[1] : d1v[1];
        float b0 = __uint_as_float(e0 << 16);
        float b1 = __uint_as_float(e0 & 0xffff0000u);
        float b2 = __uint_as_float(e1 << 16);
        float b3 = __uint_as_float(e1 & 0xffff0000u);
        p[jk][0] = fexp2(fmaf(sc[jk][0], 0.125f * LOG2E, b0));
        p[jk][1] = fexp2(fmaf(sc[jk][1], 0.125f * LOG2E, b1));
        p[jk][2] = fexp2(fmaf(sc[jk][2], 0.125f * LOG2E, b2));
        p[jk][3] = fexp2(fmaf(sc[jk][3], 0.125f * LOG2E, b3));
      }
      lsum[m] += ((p[0][0] + p[0][1]) + (p[0][2] + p[0][3]))
               + ((p[1][0] + p[1][1]) + (p[1][2] + p[1][3]));
      unsigned int A0 = cvtpk_bf16(p[0][0], p[0][1]);
      unsigned int A1 = cvtpk_bf16(p[0][2], p[0][3]);
      unsigned int B0 = cvtpk_bf16(p[1][0], p[1][1]);
      unsigned int B1 = cvtpk_bf16(p[1][2], p[1][3]);
      pl32swap(A0, B0); pl16swap(A0, B0);
      pl32swap(A1, B1); pl16swap(A1, B1);
      union { unsigned int u[4]; bf16x8 v8; } pf;
      pf.u[0] = A0; pf.u[1] = A1; pf.u[2] = B0; pf.u[3] = B1;
#pragma unroll
      for (int j = 0; j < 4; j++)
        acc[m][j] = __builtin_amdgcn_mfma_f32_16x16x32_bf16(pf.v8, bv[j], acc[m][j], 0, 0, 0);
    }
  };

#define SB() __builtin_amdgcn_sched_barrier(0)
#define WAIT4()                                                   \
  asm volatile("s_waitcnt vmcnt(4) lgkmcnt(0)" ::: "memory");     \
  __builtin_amdgcn_s_barrier();                                   \
  SB()

  // prologue: drain compiler loads (aq), then establish queue [S0, S1]
  SB();
  asm volatile("s_waitcnt vmcnt(0)" ::: "memory");
  SB();
  STAGE(0, 0); SB();
  STAGE(1, 1); SB();

#pragma unroll 1
  for (int ii = 0; ii < 10; ++ii) {
    int base = ii * 3;
    WAIT4(); STAGE(base + 2, 2); SB(); BODY(0);
    WAIT4(); STAGE(base + 3, 0); SB(); BODY(1);
    WAIT4(); STAGE(base + 4, 1); SB(); BODY(2);
  }
  // peeled iters 30 (buf 0) and 31 (buf 1); no further staging
  WAIT4(); BODY(0);
  asm volatile("s_waitcnt vmcnt(0) lgkmcnt(0)" ::: "memory");
  __builtin_amdgcn_s_barrier();
  SB();
  BODY(1);

#undef WAIT4
#undef SB

  // partial row-sums: reduce across quads -> every lane holds sum for q=l16
#pragma unroll
  for (int m = 0; m < 2; m++) {
    float s = lsum[m];
    s += __shfl_xor(s, 16);
    s += __shfl_xor(s, 32);
    lsum[m] = s;
  }

  // epilogue: self-normalized bf16 partial O + f32 partial lsum
  ushort_t* pog = PO + (long)ks * 4194304 + (long)bh * 131072 + qt * 8192;
  float* Lg = L + ks * 65536 + bh * 2048 + qt * 128;
#pragma unroll
  for (int m = 0; m < 2; m++) {
#pragma unroll
    for (int r = 0; r < 4; r++) {
      float inv = 1.0f / __shfl(lsum[m], quad * 4 + r);
      int row = w * 32 + m * 16 + quad * 4 + r;
#pragma unroll
      for (int j = 0; j < 4; j++)
        pog[row * 64 + j * 16 + l16] = f2bf(acc[m][j][r] * inv);
    }
    if (quad == 0) Lg[w * 32 + m * 16 + l16] = lsum[m];
  }
}

// ---------------------------------------------------------------------------
// Kernel 3b: combine the two k-half partials.
// O = (l0*O0n + l1*O1n) / (l0+l1).  ~25MB traffic, memory-bound.
// ---------------------------------------------------------------------------
__global__ __launch_bounds__(256) void combine_kernel(
    const ushort_t* __restrict__ PO, const float* __restrict__ L,
    ushort_t* __restrict__ aout)
{
  int idx = blockIdx.x * 256 + threadIdx.x;   // [0, 524288)
  long f = (long)idx * 8;
  int r = (int)(f >> 6);                      // row id [0, 65536)
  float l0 = L[r], l1 = L[65536 + r];
  float inv = 1.0f / (l0 + l1);
  float w0 = l0 * inv, w1 = l1 * inv;
  union { uint4 v4; ushort_t us[8]; } ua, ub, o;
  ua.v4 = ((const uint4*)PO)[idx];
  ub.v4 = ((const uint4*)(PO + 4194304))[idx];
#pragma unroll
  for (int j = 0; j < 8; j++)
    o.us[j] = f2bf(w0 * bf2f(ua.us[j]) + w1 * bf2f(ub.us[j]));
  int q = r & 127, qt = (r >> 7) & 15, bh = r >> 11;
  int b_ = bh >> 4, h = bh & 15, d0 = (int)(f & 63);
  long off = (long)(b_ * NS + qt * 128 + q) * NE + h * ND + d0;
  *(uint4*)(aout + off) = o.v4;
}

// ---------------------------------------------------------------------------
// Kernel 4: output projection, triple-buffered counted-vmcnt pipeline.
// ---------------------------------------------------------------------------
__global__ __launch_bounds__(256) void oproj_kernel(
    const ushort_t* __restrict__ A, const ushort_t* __restrict__ Wob,
    const float* __restrict__ bo, float* __restrict__ out)
{
  __shared__ __align__(16) ushort_t As[3][128 * 32];  // 24KB
  __shared__ __align__(16) ushort_t Bs[3][64 * 32];   // 12KB

  int t = threadIdx.x;
  int lane = t & 63, w = t >> 6;
  int quad = lane >> 4, l16 = lane & 15;
  int wr = w >> 1, wc = w & 1;
  int m0 = blockIdx.y * 128, f0 = blockIdx.x * 64;

  int arow = t >> 2, apart = t & 3;
  const ushort_t* Xg = A + (long)(m0 + arow) * NE + apart * 8;
  const ushort_t* Wg = Wob + (long)(f0 + arow) * NE + apart * 8;

  auto STAGE = [&](int kk, int buf) {
    int k0 = kk * 32;
    gload_lds16(Xg + k0, &As[buf][t * 8]);
    gload_lds16(Xg + k0 + 64 * NE, &As[buf][64 * 32 + t * 8]);
    gload_lds16(Wg + k0, &Bs[buf][t * 8]);
  };
  STAGE(0, 0);
  STAGE(1, 1);

  floatx4 acc[4][2] = {};
  int b = 0;
  for (int k = 0; k < 32; ++k) {
    asm volatile("s_waitcnt vmcnt(3) lgkmcnt(0)" ::: "memory");
    __builtin_amdgcn_s_barrier();
    __builtin_amdgcn_sched_barrier(0);
    int nb = (b == 0) ? 2 : b - 1;
    STAGE((k + 2) & 31, nb);
    const ushort_t* Ab = As[b];
    const ushort_t* Bb = Bs[b];
    bf16x8 af[4], bf[2];
#pragma unroll
    for (int i = 0; i < 4; i++)
      af[i] = *(const bf16x8*)(Ab + (wr * 64 + i * 16 + l16) * 32 + quad * 8);
#pragma unroll
    for (int j = 0; j < 2; j++)
      bf[j] = *(const bf16x8*)(Bb + (wc * 32 + j * 16 + l16) * 32 + quad * 8);
#pragma unroll
    for (int i = 0; i < 4; i++)
#pragma unroll
      for (int j = 0; j < 2; j++)
        acc[i][j] = __builtin_amdgcn_mfma_f32_16x16x32_bf16(af[i], bf[j], acc[i][j], 0, 0, 0);
    b = (b == 2) ? 0 : b + 1;
  }
  asm volatile("s_waitcnt vmcnt(0)" ::: "memory");

#pragma unroll
  for (int j = 0; j < 2; j++) {
    int f = f0 + wc * 32 + j * 16 + l16;
    float bval = bo[f];
#pragma unroll
    for (int i = 0; i < 4; i++) {
      int mbase = m0 + wr * 64 + i * 16 + quad * 4;
#pragma unroll
      for (int r = 0; r < 4; r++) {
        int m = mbase + r;
        out[(long)m * NE + f] = acc[i][j][r] + bval;
      }
    }
  }
}

// ---------------------------------------------------------------------------
extern "C" void kernel_launch(void* const* d_in, const int* in_sizes, int n_in,
                              void* d_out, int out_size, void* d_ws, size_t ws_size,
                              hipStream_t stream) {
  const float* query = (const float*)d_in[0];
  const float* key   = (const float*)d_in[1];
  const float* value = (const float*)d_in[2];
  const float* adj   = (const float*)d_in[3];
  const int*   mask  = (const int*)d_in[4];
  const float* Wq = (const float*)d_in[5];
  const float* bq = (const float*)d_in[6];
  const float* Wk = (const float*)d_in[7];
  const float* bk = (const float*)d_in[8];
  const float* Wv = (const float*)d_in[9];
  const float* bv = (const float*)d_in[10];
  const float* Wo = (const float*)d_in[11];
  const float* bo = (const float*)d_in[12];
  float* out = (float*)d_out;

  char* ws = (char*)d_ws;
  const size_t MB = 1ull << 20;
  ushort_t* qb   = (ushort_t*)(ws + 0 * MB);    // 8 MiB  [B*S, E] bf16 (dead after qkv)
  ushort_t* kb   = (ushort_t*)(ws + 8 * MB);    // 8 MiB  (dead after qkv)
  ushort_t* vb   = (ushort_t*)(ws + 16 * MB);   // 8 MiB  (dead after qkv)
  ushort_t* wqb  = (ushort_t*)(ws + 24 * MB);   // 2 MiB
  ushort_t* wkb  = (ushort_t*)(ws + 26 * MB);   // 2 MiB
  ushort_t* wvb  = (ushort_t*)(ws + 28 * MB);   // 2 MiB
  ushort_t* wob  = (ushort_t*)(ws + 30 * MB);   // 2 MiB (live until oproj)
  ushort_t* Qh   = (ushort_t*)(ws + 32 * MB);   // 8 MiB  [B,H,S,D]
  ushort_t* Kh   = (ushort_t*)(ws + 40 * MB);   // 8 MiB  [B,H,S,D]
  ushort_t* Vt   = (ushort_t*)(ws + 48 * MB);   // 8 MiB  [B,H,D,S]
  ushort_t* aout = (ushort_t*)(ws + 56 * MB);   // 8 MiB  [B,S,E]
  ushort_t* bias = (ushort_t*)(ws + 64 * MB);   // 16 MiB biasT [B][64kt][2048q][32k]
  // attn partials overlay the dead qb/kb/vb region:
  ushort_t* PO   = (ushort_t*)(ws + 0 * MB);    // 16 MiB: 2 x [32bh,16qt,128q,64d] bf16
  float*    Lp   = (float*)(ws + 16 * MB);      // 512 KiB: 2 x 65536 f32

  convert_kernel<<<12288, 256, 0, stream>>>(query, key, value, Wq, Wk, Wv, Wo,
                                            adj, mask, qb, kb, vb, wqb, wkb, wvb, wob, bias);
  qkv_kernel<<<dim3(8, 32, 3), 256, 0, stream>>>(qb, kb, vb, wqb, wkb, wvb,
                                                 bq, bk, bv, Qh, Kh, Vt);
  attn_kernel<<<dim3(1024), 256, 0, stream>>>(Qh, Kh, Vt, bias, PO, Lp);
  combine_kernel<<<dim3(2048), 256, 0, stream>>>(PO, Lp, aout);
  oproj_kernel<<<dim3(16, 32), 256, 0, stream>>>(aout, wob, bo, out);
}